// Round 1
// baseline (198.140 us; speedup 1.0000x reference)
//
#include <hip/hip_runtime.h>
#include <math.h>

#define HIDDEN 768

// ln(10000) = 9.210340371976184
#define NEG_LN1E4_OVER_768 (-0.011992630692677323f)  // -ln(10000)/768
#define NEG_LN1E4_OVER_256 (-0.035977892078031970f)  // -ln(10000)/256

__global__ __launch_bounds__(256) void emb_ln_kernel(
    const int*   __restrict__ input_ids,    // B*S
    const int*   __restrict__ tok_struct,   // B*S*3
    const int*   __restrict__ token_type,   // B*S
    const float* __restrict__ word_emb,     // VOCAB*768
    const float* __restrict__ type_emb,     // 2*768
    const float* __restrict__ ln_w,         // 768
    const float* __restrict__ ln_b,         // 768
    float*       __restrict__ out,          // B*S*768
    int S)
{
    const int row = blockIdx.x;            // b*S + s
    const int s   = row & (S - 1);         // S is a power of two (4096)
    const int t   = threadIdx.x;

    const int id   = input_ids[row];
    const int tt   = token_type[row];
    const int ppos = tok_struct[row * 3];  // tok_struct_vec[b, s, 0]

    // struct[h] = hs_pe[ppos, h % 256]; h % 256 == t for all three elements
    // hs_pe[p, 2k]   = sin(p * exp(2k * -ln(1e4)/256))
    // hs_pe[p, 2k+1] = cos(p * exp(2k * -ln(1e4)/256))
    const float div_hs = __expf((float)(t & ~1) * NEG_LN1E4_OVER_256);
    const float ang_hs = (float)ppos * div_hs;
    const float hsv = (t & 1) ? __cosf(ang_hs) : __sinf(ang_hs);

    const size_t wbase = (size_t)id * HIDDEN;
    const size_t tbase = (size_t)tt * HIDDEN;

    float v[3];
#pragma unroll
    for (int j = 0; j < 3; ++j) {
        const int h = t + j * 256;
        // pe[s, 2k] = sin(s * exp(2k * -ln(1e4)/768)); odd -> cos
        const float div_pe = __expf((float)(h & ~1) * NEG_LN1E4_OVER_768);
        const float ang_pe = (float)s * div_pe;
        const float pev = (h & 1) ? __cosf(ang_pe) : __sinf(ang_pe);
        v[j] = word_emb[wbase + h] + type_emb[tbase + h] + pev + hsv;
    }

    // LayerNorm over 768: block reduce sum and sumsq
    float s1 = v[0] + v[1] + v[2];
    float s2 = v[0] * v[0] + v[1] * v[1] + v[2] * v[2];

#pragma unroll
    for (int off = 32; off > 0; off >>= 1) {
        s1 += __shfl_down(s1, off, 64);
        s2 += __shfl_down(s2, off, 64);
    }

    __shared__ float ls1[4], ls2[4];
    const int wave = t >> 6;
    const int lane = t & 63;
    if (lane == 0) { ls1[wave] = s1; ls2[wave] = s2; }
    __syncthreads();

    const float fs1 = ls1[0] + ls1[1] + ls1[2] + ls1[3];
    const float fs2 = ls2[0] + ls2[1] + ls2[2] + ls2[3];

    const float inv_n = 1.0f / (float)HIDDEN;
    const float mu  = fs1 * inv_n;
    float var = fs2 * inv_n - mu * mu;
    var = fmaxf(var, 0.0f);
    const float rstd = rsqrtf(var + 1e-12f);

    const size_t obase = (size_t)row * HIDDEN;
#pragma unroll
    for (int j = 0; j < 3; ++j) {
        const int h = t + j * 256;
        out[obase + h] = (v[j] - mu) * rstd * ln_w[h] + ln_b[h];
    }
}

extern "C" void kernel_launch(void* const* d_in, const int* in_sizes, int n_in,
                              void* d_out, int out_size, void* d_ws, size_t ws_size,
                              hipStream_t stream) {
    const int*   input_ids  = (const int*)  d_in[0];
    const int*   tok_struct = (const int*)  d_in[1];
    // d_in[2] = sent_struct_vec (unused by the reference output)
    const int*   token_type = (const int*)  d_in[3];
    const float* word_emb   = (const float*)d_in[4];
    const float* type_emb   = (const float*)d_in[5];
    const float* ln_w       = (const float*)d_in[6];
    const float* ln_b       = (const float*)d_in[7];
    float* out = (float*)d_out;

    const int BS = in_sizes[0];          // B * S
    const int B  = in_sizes[2] / 128;    // sent_struct_vec is B*64*2
    const int S  = BS / B;               // 4096

    emb_ln_kernel<<<BS, 256, 0, stream>>>(input_ids, tok_struct, token_type,
                                          word_emb, type_emb, ln_w, ln_b,
                                          out, S);
}

// Round 2
// 191.418 us; speedup vs baseline: 1.0351x; 1.0351x over previous
//
#include <hip/hip_runtime.h>
#include <math.h>

#define HIDDEN 768

// -ln(10000)/768 and -ln(10000)/256
#define K768 (-0.011992630692677323f)
#define K256 (-0.035977892078031970f)
// exp(256*K768) = 10000^(-1/3), exp(512*K768) = 10000^(-2/3)
#define C256 (0.04641588833612779f)
#define C512 (0.002154434690031884f)

__global__ __launch_bounds__(256) void emb_ln_kernel(
    const int*   __restrict__ input_ids,    // B*S
    const int*   __restrict__ tok_struct,   // B*S*3
    const int*   __restrict__ token_type,   // B*S
    const float* __restrict__ word_emb,     // VOCAB*768
    const float* __restrict__ type_emb,     // 2*768
    const float* __restrict__ ln_w,         // 768
    const float* __restrict__ ln_b,         // 768
    float*       __restrict__ out,          // B*S*768
    int S)
{
    const int wave = threadIdx.x >> 6;
    const int lane = threadIdx.x & 63;
    const int row  = blockIdx.x * 4 + wave;   // one wave per token row
    const int s    = row & (S - 1);           // S = 4096 (power of two)

    const int id   = input_ids[row];
    const int tt   = token_type[row];
    const int ppos = tok_struct[row * 3];

    const int h0 = lane * 4;                  // lane owns h = h0 + 256*j + c

    // struct component: hs_pe[ppos, h % 256]; h % 256 == h0 + c for all j
    const float d0 = __expf((float)h0 * K256);
    const float d1 = __expf((float)(h0 + 2) * K256);
    const float pp = (float)ppos;
    float hs[4];
    hs[0] = __sinf(pp * d0);
    hs[1] = __cosf(pp * d0);
    hs[2] = __sinf(pp * d1);
    hs[3] = __cosf(pp * d1);

    // pe divisors: exp((h0 + 256j + {0,2}) * K768) = e{0,2} * scale_j
    const float e0 = __expf((float)h0 * K768);
    const float e2 = __expf((float)(h0 + 2) * K768);
    const float fs = (float)s;

    const float4* wrow = (const float4*)(word_emb + (size_t)id * HIDDEN);
    const float4* trow = (const float4*)(type_emb + (size_t)tt * HIDDEN);

    float v[12];
#pragma unroll
    for (int j = 0; j < 3; ++j) {
        const float scale = (j == 0) ? 1.0f : (j == 1 ? C256 : C512);
        const float a0 = fs * (e0 * scale);
        const float a1 = fs * (e2 * scale);
        const float pe0 = __sinf(a0);
        const float pe1 = __cosf(a0);
        const float pe2 = __sinf(a1);
        const float pe3 = __cosf(a1);

        const float4 w  = wrow[lane + 64 * j];
        const float4 ty = trow[lane + 64 * j];

        v[4 * j + 0] = w.x + ty.x + pe0 + hs[0];
        v[4 * j + 1] = w.y + ty.y + pe1 + hs[1];
        v[4 * j + 2] = w.z + ty.z + pe2 + hs[2];
        v[4 * j + 3] = w.w + ty.w + pe3 + hs[3];
    }

    // LayerNorm over 768: wave-level butterfly reduce (no LDS, no barrier)
    float s1 = 0.0f, s2 = 0.0f;
#pragma unroll
    for (int i = 0; i < 12; ++i) {
        s1 += v[i];
        s2 = fmaf(v[i], v[i], s2);
    }
#pragma unroll
    for (int off = 1; off < 64; off <<= 1) {
        s1 += __shfl_xor(s1, off, 64);
        s2 += __shfl_xor(s2, off, 64);
    }

    const float inv_n = 1.0f / (float)HIDDEN;
    const float mu  = s1 * inv_n;
    float var = s2 * inv_n - mu * mu;
    var = fmaxf(var, 0.0f);
    const float rstd = rsqrtf(var + 1e-12f);

    const float4* wv = (const float4*)ln_w;
    const float4* bv = (const float4*)ln_b;
    float4* orow = (float4*)(out + (size_t)row * HIDDEN);
#pragma unroll
    for (int j = 0; j < 3; ++j) {
        const float4 g = wv[lane + 64 * j];
        const float4 b = bv[lane + 64 * j];
        float4 r;
        r.x = (v[4 * j + 0] - mu) * rstd * g.x + b.x;
        r.y = (v[4 * j + 1] - mu) * rstd * g.y + b.y;
        r.z = (v[4 * j + 2] - mu) * rstd * g.z + b.z;
        r.w = (v[4 * j + 3] - mu) * rstd * g.w + b.w;
        orow[lane + 64 * j] = r;
    }
}

extern "C" void kernel_launch(void* const* d_in, const int* in_sizes, int n_in,
                              void* d_out, int out_size, void* d_ws, size_t ws_size,
                              hipStream_t stream) {
    const int*   input_ids  = (const int*)  d_in[0];
    const int*   tok_struct = (const int*)  d_in[1];
    // d_in[2] = sent_struct_vec (unused by the reference output)
    const int*   token_type = (const int*)  d_in[3];
    const float* word_emb   = (const float*)d_in[4];
    const float* type_emb   = (const float*)d_in[5];
    const float* ln_w       = (const float*)d_in[6];
    const float* ln_b       = (const float*)d_in[7];
    float* out = (float*)d_out;

    const int BS = in_sizes[0];          // B * S
    const int B  = in_sizes[2] / 128;    // sent_struct_vec is B*64*2
    const int S  = BS / B;               // 4096

    // one wave per row, 4 rows per 256-thread block
    emb_ln_kernel<<<BS / 4, 256, 0, stream>>>(input_ids, tok_struct, token_type,
                                              word_emb, type_emb, ln_w, ln_b,
                                              out, S);
}

// Round 4
// 191.274 us; speedup vs baseline: 1.0359x; 1.0008x over previous
//
#include <hip/hip_runtime.h>
#include <math.h>

#define HIDDEN 768

// -ln(10000)/768 and -ln(10000)/256
#define K768 (-0.011992630692677323f)
#define K256 (-0.035977892078031970f)
// exp(256*K768) = 10000^(-1/3), exp(512*K768) = 10000^(-2/3)
#define C256 (0.04641588833612779f)
#define C512 (0.002154434690031884f)

typedef float nfloat4 __attribute__((ext_vector_type(4)));  // native vec for NT stores

__global__ __launch_bounds__(256) void emb_ln_kernel(
    const int*   __restrict__ input_ids,    // B*S
    const int*   __restrict__ tok_struct,   // B*S*3
    const int*   __restrict__ token_type,   // B*S
    const float* __restrict__ word_emb,     // VOCAB*768
    const float* __restrict__ type_emb,     // 2*768
    const float* __restrict__ ln_w,         // 768
    const float* __restrict__ ln_b,         // 768
    float*       __restrict__ out,          // B*S*768
    int S)
{
    const int wave = threadIdx.x >> 6;
    const int lane = threadIdx.x & 63;
    const int pair = blockIdx.x * 4 + wave;   // one wave per TWO token rows
    const int row0 = pair * 2;
    const int row1 = row0 + 1;

    const int id0   = input_ids[row0];
    const int id1   = input_ids[row1];
    const int tt0   = token_type[row0];
    const int tt1   = token_type[row1];
    const int ppos0 = tok_struct[row0 * 3];
    const int ppos1 = tok_struct[row1 * 3];

    const float4* wrow0 = (const float4*)(word_emb + (size_t)id0 * HIDDEN);
    const float4* wrow1 = (const float4*)(word_emb + (size_t)id1 * HIDDEN);
    const float4* trow0 = (const float4*)(type_emb + (size_t)tt0 * HIDDEN);
    const float4* trow1 = (const float4*)(type_emb + (size_t)tt1 * HIDDEN);

    // issue all 12 independent gather loads up front (max MLP)
    float4 w0[3], w1[3], ty0[3], ty1[3];
#pragma unroll
    for (int j = 0; j < 3; ++j) {
        w0[j]  = wrow0[lane + 64 * j];
        w1[j]  = wrow1[lane + 64 * j];
        ty0[j] = trow0[lane + 64 * j];
        ty1[j] = trow1[lane + 64 * j];
    }

    const int h0 = lane * 4;   // lane owns h = h0 + 256*j + c

    // shared-across-rows divisors
    const float d0 = __expf((float)h0 * K256);
    const float d1 = __expf((float)(h0 + 2) * K256);
    const float e0 = __expf((float)h0 * K768);
    const float e2 = __expf((float)(h0 + 2) * K768);

    const int s0 = row0 & (S - 1);
    const int s1i = row1 & (S - 1);

    float v0[12], v1[12];
#pragma unroll
    for (int r = 0; r < 2; ++r) {
        const float pp = (float)(r == 0 ? ppos0 : ppos1);
        const float fs = (float)(r == 0 ? s0 : s1i);
        float* v = (r == 0) ? v0 : v1;
        const float4* w  = (r == 0) ? w0  : w1;
        const float4* ty = (r == 0) ? ty0 : ty1;

        float hs[4];
        hs[0] = __sinf(pp * d0);
        hs[1] = __cosf(pp * d0);
        hs[2] = __sinf(pp * d1);
        hs[3] = __cosf(pp * d1);

#pragma unroll
        for (int j = 0; j < 3; ++j) {
            const float scale = (j == 0) ? 1.0f : (j == 1 ? C256 : C512);
            const float a0 = fs * (e0 * scale);
            const float a1 = fs * (e2 * scale);
            v[4 * j + 0] = w[j].x + ty[j].x + __sinf(a0) + hs[0];
            v[4 * j + 1] = w[j].y + ty[j].y + __cosf(a0) + hs[1];
            v[4 * j + 2] = w[j].z + ty[j].z + __sinf(a1) + hs[2];
            v[4 * j + 3] = w[j].w + ty[j].w + __cosf(a1) + hs[3];
        }
    }

    // LayerNorm reduce for both rows, interleaved butterfly (no LDS/barrier)
    float a1 = 0.0f, a2 = 0.0f, b1 = 0.0f, b2 = 0.0f;
#pragma unroll
    for (int i = 0; i < 12; ++i) {
        a1 += v0[i];
        a2 = fmaf(v0[i], v0[i], a2);
        b1 += v1[i];
        b2 = fmaf(v1[i], v1[i], b2);
    }
#pragma unroll
    for (int off = 1; off < 64; off <<= 1) {
        a1 += __shfl_xor(a1, off, 64);
        a2 += __shfl_xor(a2, off, 64);
        b1 += __shfl_xor(b1, off, 64);
        b2 += __shfl_xor(b2, off, 64);
    }

    const float inv_n = 1.0f / (float)HIDDEN;
    const float mu0 = a1 * inv_n;
    const float mu1 = b1 * inv_n;
    const float rstd0 = rsqrtf(fmaxf(a2 * inv_n - mu0 * mu0, 0.0f) + 1e-12f);
    const float rstd1 = rsqrtf(fmaxf(b2 * inv_n - mu1 * mu1, 0.0f) + 1e-12f);

    const float4* wv = (const float4*)ln_w;
    const float4* bv = (const float4*)ln_b;
    nfloat4* orow0 = (nfloat4*)(out + (size_t)row0 * HIDDEN);
    nfloat4* orow1 = (nfloat4*)(out + (size_t)row1 * HIDDEN);
#pragma unroll
    for (int j = 0; j < 3; ++j) {
        const float4 g = wv[lane + 64 * j];
        const float4 b = bv[lane + 64 * j];
        nfloat4 r0, r1;
        r0.x = (v0[4 * j + 0] - mu0) * rstd0 * g.x + b.x;
        r0.y = (v0[4 * j + 1] - mu0) * rstd0 * g.y + b.y;
        r0.z = (v0[4 * j + 2] - mu0) * rstd0 * g.z + b.z;
        r0.w = (v0[4 * j + 3] - mu0) * rstd0 * g.w + b.w;
        r1.x = (v1[4 * j + 0] - mu1) * rstd1 * g.x + b.x;
        r1.y = (v1[4 * j + 1] - mu1) * rstd1 * g.y + b.y;
        r1.z = (v1[4 * j + 2] - mu1) * rstd1 * g.z + b.z;
        r1.w = (v1[4 * j + 3] - mu1) * rstd1 * g.w + b.w;
        __builtin_nontemporal_store(r0, &orow0[lane + 64 * j]);
        __builtin_nontemporal_store(r1, &orow1[lane + 64 * j]);
    }
}

extern "C" void kernel_launch(void* const* d_in, const int* in_sizes, int n_in,
                              void* d_out, int out_size, void* d_ws, size_t ws_size,
                              hipStream_t stream) {
    const int*   input_ids  = (const int*)  d_in[0];
    const int*   tok_struct = (const int*)  d_in[1];
    // d_in[2] = sent_struct_vec (unused by the reference output)
    const int*   token_type = (const int*)  d_in[3];
    const float* word_emb   = (const float*)d_in[4];
    const float* type_emb   = (const float*)d_in[5];
    const float* ln_w       = (const float*)d_in[6];
    const float* ln_b       = (const float*)d_in[7];
    float* out = (float*)d_out;

    const int BS = in_sizes[0];          // B * S
    const int B  = in_sizes[2] / 128;    // sent_struct_vec is B*64*2
    const int S  = BS / B;               // 4096

    // one wave per 2 rows, 4 waves per block -> 8 rows per block
    emb_ln_kernel<<<BS / 8, 256, 0, stream>>>(input_ids, tok_struct, token_type,
                                              word_emb, type_emb, ln_w, ln_b,
                                              out, S);
}

// Round 5
// 188.746 us; speedup vs baseline: 1.0498x; 1.0134x over previous
//
#include <hip/hip_runtime.h>
#include <math.h>

#define HIDDEN 768

// -ln(10000)/768 and -ln(10000)/256
#define K768 (-0.011992630692677323f)
#define K256 (-0.035977892078031970f)
// exp(256*K768) = 10000^(-1/3), exp(512*K768) = 10000^(-2/3)
#define C256 (0.04641588833612779f)
#define C512 (0.002154434690031884f)

typedef float nfloat4 __attribute__((ext_vector_type(4)));  // native vec for NT stores

__global__ __launch_bounds__(256) void emb_ln_kernel(
    const int*   __restrict__ input_ids,    // B*S
    const int*   __restrict__ tok_struct,   // B*S*3
    const int*   __restrict__ token_type,   // B*S
    const float* __restrict__ word_emb,     // VOCAB*768
    const float* __restrict__ type_emb,     // 2*768
    const float* __restrict__ ln_w,         // 768
    const float* __restrict__ ln_b,         // 768
    float*       __restrict__ out,          // B*S*768
    int S, int BS)
{
    const int wave = threadIdx.x >> 6;
    const int lane = threadIdx.x & 63;
    const int gw   = blockIdx.x * 4 + wave;   // global wave id
    const int NW   = gridDim.x * 4;           // total waves

    const int h0 = lane * 4;   // lane owns h = h0 + 256*j + c

    // per-lane constants, computed once per wave
    const float d0 = __expf((float)h0 * K256);
    const float d1 = __expf((float)(h0 + 2) * K256);
    const float e0 = __expf((float)h0 * K768);
    const float e2 = __expf((float)(h0 + 2) * K768);

    // ln params + both type_emb rows (TYPE_VOCAB == 2), loaded once per wave
    float4 g[3], bb[3], t0[3], t1[3];
    const float4* wv = (const float4*)ln_w;
    const float4* bv = (const float4*)ln_b;
    const float4* te = (const float4*)type_emb;
#pragma unroll
    for (int j = 0; j < 3; ++j) {
        g[j]  = wv[lane + 64 * j];
        bb[j] = bv[lane + 64 * j];
        t0[j] = te[lane + 64 * j];
        t1[j] = te[lane + 64 * j + 192];   // row 1 at offset 768 floats = 192 float4
    }

    int r = gw;
    if (r >= BS) return;

    // prologue: issue row r's loads
    int id = input_ids[r];
    int tt = token_type[r];
    int pp = tok_struct[3 * r];
    float4 w[3];
    {
        const float4* wrow = (const float4*)(word_emb + (size_t)id * HIDDEN);
#pragma unroll
        for (int j = 0; j < 3; ++j) w[j] = wrow[lane + 64 * j];
    }

    while (true) {
        const int rn = r + NW;
        const bool has_next = rn < BS;

        // issue next row's gather before computing current (1-deep pipeline)
        int idn = 0, ttn = 0, ppn = 0;
        float4 wn[3];
        if (has_next) {
            idn = input_ids[rn];
            ttn = token_type[rn];
            ppn = tok_struct[3 * rn];
            const float4* wrow = (const float4*)(word_emb + (size_t)idn * HIDDEN);
#pragma unroll
            for (int j = 0; j < 3; ++j) wn[j] = wrow[lane + 64 * j];
        }

        // ---- compute current row ----
        const float fpp = (float)pp;
        float hs[4];
        hs[0] = __sinf(fpp * d0);
        hs[1] = __cosf(fpp * d0);
        hs[2] = __sinf(fpp * d1);
        hs[3] = __cosf(fpp * d1);

        const float fs = (float)(r & (S - 1));

        float v[12];
#pragma unroll
        for (int j = 0; j < 3; ++j) {
            const float scale = (j == 0) ? 1.0f : (j == 1 ? C256 : C512);
            const float a0 = fs * (e0 * scale);
            const float a1 = fs * (e2 * scale);
            const float4 ty = tt ? t1[j] : t0[j];
            v[4 * j + 0] = w[j].x + ty.x + __sinf(a0) + hs[0];
            v[4 * j + 1] = w[j].y + ty.y + __cosf(a0) + hs[1];
            v[4 * j + 2] = w[j].z + ty.z + __sinf(a1) + hs[2];
            v[4 * j + 3] = w[j].w + ty.w + __cosf(a1) + hs[3];
        }

        float s1 = 0.0f, s2 = 0.0f;
#pragma unroll
        for (int i = 0; i < 12; ++i) {
            s1 += v[i];
            s2 = fmaf(v[i], v[i], s2);
        }
#pragma unroll
        for (int off = 1; off < 64; off <<= 1) {
            s1 += __shfl_xor(s1, off, 64);
            s2 += __shfl_xor(s2, off, 64);
        }

        const float inv_n = 1.0f / (float)HIDDEN;
        const float mu = s1 * inv_n;
        const float rstd = rsqrtf(fmaxf(s2 * inv_n - mu * mu, 0.0f) + 1e-12f);

        nfloat4* orow = (nfloat4*)(out + (size_t)r * HIDDEN);
#pragma unroll
        for (int j = 0; j < 3; ++j) {
            nfloat4 rr;
            rr.x = (v[4 * j + 0] - mu) * rstd * g[j].x + bb[j].x;
            rr.y = (v[4 * j + 1] - mu) * rstd * g[j].y + bb[j].y;
            rr.z = (v[4 * j + 2] - mu) * rstd * g[j].z + bb[j].z;
            rr.w = (v[4 * j + 3] - mu) * rstd * g[j].w + bb[j].w;
            __builtin_nontemporal_store(rr, &orow[lane + 64 * j]);
        }

        if (!has_next) break;
        id = idn; tt = ttn; pp = ppn;
        w[0] = wn[0]; w[1] = wn[1]; w[2] = wn[2];
        r = rn;
    }
}

extern "C" void kernel_launch(void* const* d_in, const int* in_sizes, int n_in,
                              void* d_out, int out_size, void* d_ws, size_t ws_size,
                              hipStream_t stream) {
    const int*   input_ids  = (const int*)  d_in[0];
    const int*   tok_struct = (const int*)  d_in[1];
    // d_in[2] = sent_struct_vec (unused by the reference output)
    const int*   token_type = (const int*)  d_in[3];
    const float* word_emb   = (const float*)d_in[4];
    const float* type_emb   = (const float*)d_in[5];
    const float* ln_w       = (const float*)d_in[6];
    const float* ln_b       = (const float*)d_in[7];
    float* out = (float*)d_out;

    const int BS = in_sizes[0];          // B * S
    const int B  = in_sizes[2] / 128;    // sent_struct_vec is B*64*2
    const int S  = BS / B;               // 4096

    // persistent-ish grid: 2048 blocks x 4 waves = 8192 waves, 4 rows/wave,
    // 1-deep software pipeline (next row's gather in flight during compute)
    int blocks = 2048;
    if (blocks * 4 > BS) blocks = (BS + 3) / 4;
    emb_ln_kernel<<<blocks, 256, 0, stream>>>(input_ids, tok_struct, token_type,
                                              word_emb, type_emb, ln_w, ln_b,
                                              out, S, BS);
}